// Round 11
// baseline (1063.307 us; speedup 1.0000x reference)
//
#include <hip/hip_runtime.h>
#include <cstdint>
#include <cstddef>

// Problem constants
#define B_   1024
#define L_   64
#define H_   512
#define NBLK 256

// Workspace layout (bytes). Total 12,061,696 (~11.5 MiB).
//  WB  : transposed bf16 weights  BT_j[n][k]  (j0: 512x512, j1-3: 512x1024)
//  SB  : state buffers bf16 [layer j][parity], each in 32-ROW A-FRAGMENT
//        TILE ORDER: short idx(row,k) = (row>>5)*16384 + (k>>3)*256
//                                      + (row&31)*8 + (k&7)
//        (wave's 32-row x 16-k MFMA A-fragment = 1 KB contiguous)
//  BAR : SLOT array: 8 groups x 32 blocks x u32 (128 B per group line)
//  XCD : per-block XCC_ID table (256 x u32)
#define WB_OFF   0u
#define SB_OFF   3670016u
#define BAR_OFF  12058624u
#define XCD_OFF  12060672u

typedef __attribute__((ext_vector_type(8))) short short8;
typedef __attribute__((ext_vector_type(4))) float f32x4;
typedef __attribute__((ext_vector_type(16))) float f32x16;
typedef unsigned long long u64;

__device__ __forceinline__ unsigned short f2bf(float f) {
  unsigned u = __float_as_uint(f);
  u += 0x7fffu + ((u >> 16) & 1u);   // RNE
  return (unsigned short)(u >> 16);
}

__device__ __forceinline__ float bf2f(unsigned short s) {
  return __uint_as_float(((unsigned)s) << 16);
}

__device__ __forceinline__ void async16(const void* g, void* l) {
  __builtin_amdgcn_global_load_lds(
      (const __attribute__((address_space(1))) void*)g,
      (__attribute__((address_space(3))) void*)l, 16, 0, 0);
}

// Device-coherent (agent-scope, relaxed) ops: L1-bypass, no fences.
__device__ __forceinline__ u64 cohload(const u64* p) {
  return __hip_atomic_load((u64*)p, __ATOMIC_RELAXED, __HIP_MEMORY_SCOPE_AGENT);
}
__device__ __forceinline__ void cohstore(u64* p, u64 v) {
  __hip_atomic_store(p, v, __ATOMIC_RELAXED, __HIP_MEMORY_SCOPE_AGENT);
}
__device__ __forceinline__ unsigned cohload32(const unsigned* p) {
  return __hip_atomic_load((unsigned*)p, __ATOMIC_RELAXED, __HIP_MEMORY_SCOPE_AGENT);
}
__device__ __forceinline__ void cohstore32(unsigned* p, unsigned v) {
  __hip_atomic_store(p, v, __ATOMIC_RELAXED, __HIP_MEMORY_SCOPE_AGENT);
}

// ---------------------------------------------------------------------------
// Init: transpose+convert weights fp32->bf16 [N][K], zero SB + BAR + XCD.
// ---------------------------------------------------------------------------
__global__ __launch_bounds__(256) void init_kernel(
    const float* __restrict__ Wc, const float* __restrict__ Win_rest,
    char* __restrict__ ws)
{
  const unsigned bb = blockIdx.x;
  const int tid = threadIdx.x;
  if (bb < 448u) {
    __shared__ float tile[64][65];
    int m, tt;
    if (bb < 64u) { m = 0; tt = (int)bb; }
    else { m = 1 + (int)((bb - 64u) >> 7); tt = (int)((bb - 64u) & 127u); }
    const int Km = (m == 0) ? 512 : 1024;
    const int nkt = Km >> 6;
    const int tk = tt % nkt, tn = tt / nkt;
    const int k0 = tk << 6, n0 = tn << 6;
    const int rr = tid >> 4, cc = (tid & 15) << 2;
#pragma unroll
    for (int qq = 0; qq < 4; ++qq) {
      const int row = rr + qq * 16;     // local k
      const int kg = k0 + row;
      const float* src;
      if (m == 0)        src = Wc + (size_t)kg * 512 + n0 + cc;
      else if (kg < 512) src = Wc + ((size_t)m * 512 + kg) * 512 + n0 + cc;
      else               src = Win_rest + ((size_t)(m - 1) * 512 + (kg - 512)) * 512 + n0 + cc;
      const float4 v = *(const float4*)src;
      tile[row][cc + 0] = v.x; tile[row][cc + 1] = v.y;
      tile[row][cc + 2] = v.z; tile[row][cc + 3] = v.w;
    }
    __syncthreads();
    unsigned short* dst = (unsigned short*)(ws + WB_OFF);
    const size_t base = (m == 0) ? 0 : (size_t)262144 + (size_t)(m - 1) * 524288;
#pragma unroll
    for (int qq = 0; qq < 4; ++qq) {
      const int nl = rr + qq * 16;
      const int kl = (tid & 15) << 2;
      ushort4 o;
      o.x = f2bf(tile[kl + 0][nl]); o.y = f2bf(tile[kl + 1][nl]);
      o.z = f2bf(tile[kl + 2][nl]); o.w = f2bf(tile[kl + 3][nl]);
      *(ushort4*)(dst + base + (size_t)(n0 + nl) * Km + k0 + kl) = o;
    }
  } else {
    // zero SB (8,388,608 B) + BAR (2,048 B) + XCD (1,024 B) = 524,480 x 16 B
    f32x4* z = (f32x4*)(ws + SB_OFF);
    const unsigned idx = (bb - 448u) * 256u + (unsigned)tid;
    const f32x4 zero = {0.f, 0.f, 0.f, 0.f};
    for (unsigned u = idx; u < 524480u; u += 16384u) z[u] = zero;
  }
}

// ---------------------------------------------------------------------------
// Persistent kernel. 256 blocks x 512 threads = 8 groups x (4 layers x 8
// col-slices). 8 waves/block = 4 row-tiles (32 rows) x 2 K-halves.
// 32x32x16 MFMA: wave computes partial C[32x64] over its K-half with
// direct global->register A-fragments (1 KB contiguous, depth-8 prefetch)
// and LDS-pinned B (1 b128/MFMA). K-half partials exchanged through LDS
// (rows 0-15 <-> 16-31 = acc regs 0-7 / 8-15). Sync: per-block slot store
// + 32-lane ballot poll (no atomic RMW chain). Fast/fallback store paths
// per runtime XCD-affinity check as before.
// ---------------------------------------------------------------------------
__global__ __launch_bounds__(512) void rnn_persistent(
    const int* __restrict__ x, const float* __restrict__ Win0,
    const float* __restrict__ bc, const float* __restrict__ Wout,
    const float* __restrict__ bout, char* __restrict__ ws,
    float* __restrict__ out)
{
  __shared__ short Bl[2 * 128 * 256];   // 128 KiB weight slice (ct,kc,c5,e)
  __shared__ float Ex[8192];            // 32 KiB exchange buf / Ctile overlay

  const int tid = threadIdx.x;
  const int wave = tid >> 6, lane = tid & 63;
  const int blk = (int)blockIdx.x;
  const int g  = blk & 7;            // row-group (XCD-affine under %8 heuristic)
  const int bi = blk >> 3;           // 0..31 within group
  const int j  = bi >> 3;            // layer 0..3
  const int bn = bi & 7;             // col-slice 0..7
  const int bm0 = g * 128;
  const int bn0 = bn * 64;
  const int bnc = bn0 >> 3;          // first k-chunk of our cols
  const int wrow = wave & 3;         // row-tile 0..3
  const int kh   = wave >> 2;        // K-half 0..1
  const int rowbase = bm0 + wrow * 32;
  const size_t rowOff = (size_t)(rowbase >> 5) * 16384;

  const unsigned short* WB = (const unsigned short*)(ws + WB_OFF);
  unsigned short* SB = (unsigned short*)(ws + SB_OFF);
  unsigned* SLOT = (unsigned*)(ws + BAR_OFF);
  unsigned* XT = (unsigned*)(ws + XCD_OFF);

  const int Kc   = (j == 0) ? 512 : 1024;
  const int KcD8 = Kc >> 3;
  const int Kc2  = Kc >> 1;
  const int nk16 = Kc2 >> 4;         // k-steps (K=16): 16 (j0) or 32
  const int khB  = kh * (Kc2 >> 3);  // B-chunk base for this K-half
  const int kcA0 = (j == 0) ? kh * 32 : 0;  // A-chunk base within source
  const int brow_lp = bm0 + bi * 4 + wave;  // logprob row (waves 0..3)

  const int q32 = lane >> 5, l31 = lane & 31;

  // ---- one-time: pin B slice in LDS, chunk-linear (dest = base + lane*16)
  {
    const unsigned short* Wj = WB + ((j == 0) ? (size_t)0
                                   : ((size_t)262144 + (size_t)(j - 1) * 524288));
    const int totalci = 64 * KcD8;
    const int shiftK = (j == 0) ? 6 : 7;
    for (int ci = tid; ci < totalci; ci += 512) {
      const int c5 = ci & 31;
      const int kc = (ci >> 5) & (KcD8 - 1);
      const int ct = ci >> (5 + shiftK);
      async16(Wj + (size_t)(bn0 + ct * 32 + c5) * Kc + kc * 8,
              (short*)Bl + (size_t)ci * 8);
    }
  }

  // ---- XCD-affinity check: publish XCC_ID, poll-all, verify per wave.
  const unsigned myxcd = __builtin_amdgcn_s_getreg(6164);  // hwreg(20,0,4)
  if (tid == 0) cohstore32(&XT[blk], myxcd + 1u);
  unsigned xv = 1;
  {
    unsigned spins = 0;
    for (;;) {
      xv = 1;
      if (lane < 32) xv = cohload32(&XT[lane * 8 + g]);
      if (__ballot(xv != 0) == ~0ull) break;
      __builtin_amdgcn_s_sleep(2);
      if (++spins > (1u << 20)) break;
    }
  }
  const unsigned xv0 = __shfl(xv, 0);
  const bool fast = (__ballot(lane >= 32 || xv == xv0) == ~0ull);
  __syncthreads();   // also drains this wave's B staging loads

  // ---- hoist per-round-invariant weights into registers
  float wout0[8], wout1[8];
#pragma unroll
  for (int i = 0; i < 8; ++i) {
    const int n = lane * 8 + i;
    wout0[i] = Wout[n * 2 + 0];
    wout1[i] = Wout[n * 2 + 1];
  }
  const float bo0 = bout[0], bo1 = bout[1];
  float bcc[2], w0c[2], w1c[2];
#pragma unroll
  for (int ct2 = 0; ct2 < 2; ++ct2) {
    const int col = bn0 + ct2 * 32 + l31;
    bcc[ct2] = bc[j * H_ + col];
    w0c[ct2] = Win0[col];
    w1c[ct2] = Win0[H_ + col];
  }

  float runLP = 0.f;

#pragma clang loop unroll(disable)
  for (int r = 0; r <= 67; ++r) {
    const int pprev = (r + 1) & 1, pcur = r & 1;
    const int t = r - j;
    const bool active = (t >= 0 && t <= 63);

    const unsigned short* Ssrc = SB + (size_t)(j * 2 + pprev) * (B_ * H_);
    const unsigned short* Psrc = (j > 0)
        ? SB + (size_t)((j - 1) * 2 + pprev) * (B_ * H_) : (const unsigned short*)0;
    unsigned short* Dst = SB + (size_t)(j * 2 + pcur) * (B_ * H_);
    const unsigned short* Asrc = (j > 0 && kh == 1) ? Psrc : Ssrc;

    // A-fragment load (16 B/lane, wave = 1 KB contiguous) for kstep kk.
    auto loadTo = [&](int kk, u64 (&st)[2]) {
      const u64* gp = (const u64*)(Asrc + rowOff
                        + (size_t)(kcA0 + 2 * kk + q32) * 256 + l31 * 8);
      st[0] = cohload(gp);
      st[1] = cohload(gp + 1);
    };

    u64 s[8][2];
    if (active) {
#pragma unroll
      for (int p = 0; p < 8; ++p) loadTo(p, s[p]);
    }

    // ---- logprob for t' = r-4 (waves 0..3), overlaps the prefetch latency
    if (r >= 4 && wave < 4) {
      const int tl = r - 4;
      const unsigned short* h3 = SB + (size_t)(3 * 2 + pprev) * (B_ * H_)
                                    + (size_t)(brow_lp >> 5) * 16384
                                    + (size_t)(brow_lp & 31) * 8;
      const u64* hp = (const u64*)(h3 + (size_t)lane * 256);
      const u64 hw0 = cohload(hp);
      const u64 hw1 = cohload(hp + 1);
      float z0 = 0.f, z1 = 0.f;
#pragma unroll
      for (int i = 0; i < 8; ++i) {
        const u64 hw = (i < 4) ? hw0 : hw1;
        const float h = bf2f((unsigned short)((hw >> (16 * (i & 3))) & 0xffffu));
        z0 = fmaf(h, wout0[i], z0);
        z1 = fmaf(h, wout1[i], z1);
      }
#pragma unroll
      for (int off = 32; off > 0; off >>= 1) {
        z0 += __shfl_down(z0, off);
        z1 += __shfl_down(z1, off);
      }
      if (lane == 0) {
        z0 += bo0; z1 += bo1;
        const float mx = fmaxf(z0, z1), mn = fminf(z0, z1);
        const float lse = mx + log1pf(__expf(mn - mx));
        const int xt = x[brow_lp * L_ + tl];
        float lp = ((xt == 0) ? z0 : z1) - lse;
        if (!(lp == lp)) lp = -35.0f;   // nan_to_num
        runLP += lp;
        if (tl == 63) out[brow_lp] = 0.5f * runLP;   // LOG_PROB_FACTOR
      }
    }

    if (active) {
      // ---- k-loop: 32x32x16 MFMA, 2 col-tiles, depth-8 A prefetch
      f32x16 acc0 = {};
      f32x16 acc1 = {};
      auto kstep = [&](int kk, u64 (&st)[2]) {
        short8 af;
        __builtin_memcpy(&af, &st[0], 16);
        if (kk + 8 < nk16) loadTo(kk + 8, st);
        const int kc = khB + 2 * kk + q32;
        const short8 b0 = *(const short8*)((short*)Bl + (size_t)kc * 256 + l31 * 8);
        acc0 = __builtin_amdgcn_mfma_f32_32x32x16_bf16(af, b0, acc0, 0, 0, 0);
        const short8 b1 = *(const short8*)((short*)Bl
                          + (size_t)(KcD8 + kc) * 256 + l31 * 8);
        acc1 = __builtin_amdgcn_mfma_f32_32x32x16_bf16(af, b1, acc1, 0, 0, 0);
      };
#pragma clang loop unroll(disable)
      for (int kk = 0; kk < nk16; kk += 8) {
        kstep(kk + 0, s[0]); kstep(kk + 1, s[1]);
        kstep(kk + 2, s[2]); kstep(kk + 3, s[3]);
        kstep(kk + 4, s[4]); kstep(kk + 5, s[5]);
        kstep(kk + 6, s[6]); kstep(kk + 7, s[7]);
      }

      // ---- exchange K-half partials: rows split = acc regs 0-7 / 8-15
      float outg[2][8], own[2][8];
      if (kh == 0) {
#pragma unroll
        for (int e = 0; e < 8; ++e) {
          outg[0][e] = acc0[8 + e]; outg[1][e] = acc1[8 + e];
          own[0][e]  = acc0[e];     own[1][e]  = acc1[e];
        }
      } else {
#pragma unroll
        for (int e = 0; e < 8; ++e) {
          outg[0][e] = acc0[e];     outg[1][e] = acc1[e];
          own[0][e]  = acc0[8 + e]; own[1][e]  = acc1[8 + e];
        }
      }
      const int exw = (wrow * 2 + kh) * 1024;
      const int exr = (wrow * 2 + (1 - kh)) * 1024;
#pragma unroll
      for (int ct2 = 0; ct2 < 2; ++ct2)
#pragma unroll
        for (int half = 0; half < 2; ++half) {
          f32x4 v;
#pragma unroll
          for (int i = 0; i < 4; ++i) v[i] = outg[ct2][half * 4 + i];
          *(f32x4*)(Ex + exw + (ct2 * 2 + half) * 256 + lane * 4) = v;
        }
      __syncthreads();
      float fin[2][8];
#pragma unroll
      for (int ct2 = 0; ct2 < 2; ++ct2)
#pragma unroll
        for (int half = 0; half < 2; ++half) {
          const f32x4 v = *(const f32x4*)(Ex + exr + (ct2 * 2 + half) * 256 + lane * 4);
#pragma unroll
          for (int i = 0; i < 4; ++i)
            fin[ct2][half * 4 + i] = own[ct2][half * 4 + i] + v[i];
        }
      __syncthreads();   // all Ex reads done before Ctile overlay writes

      // ---- epilogue: bias (+Win0) + elu -> padded Ctile (stride 72 shorts)
      short* Ct = (short*)Ex + wave * 1152;
#pragma unroll
      for (int e = 0; e < 8; ++e) {
        const int lr = (e & 3) + 8 * (e >> 2) + 4 * q32;   // local row 0..15
        const int brow = rowbase + kh * 16 + lr;
        int xprev = 0;
        if (j == 0 && t > 0) xprev = x[brow * L_ + (t - 1)];
#pragma unroll
        for (int ct2 = 0; ct2 < 2; ++ct2) {
          float pre = fin[ct2][e] + bcc[ct2];
          if (j == 0 && t > 0) pre += (xprev ? w1c[ct2] : w0c[ct2]);
          const float h = (pre > 0.f) ? pre : (__expf(pre) - 1.0f);
          Ct[lr * 72 + ct2 * 32 + l31] = (short)f2bf(h);
        }
      }
      // same-wave DS in-order: readback needs no barrier. Store in SB tile
      // order: contiguous 256 B runs per 16 lanes.
#pragma unroll
      for (int it = 0; it < 2; ++it) {
        const int idx = it * 64 + lane;       // 0..127
        const int ch = idx >> 4;              // k-chunk 0..7
        const int row16 = idx & 15;
        const u64* p = (const u64*)(Ct + row16 * 72 + ch * 8);
        const u64 d0 = p[0], d1 = p[1];
        u64* gdst = (u64*)(Dst + rowOff + (size_t)(bnc + ch) * 256
                           + (size_t)(kh * 16 + row16) * 8);
        if (fast) {                      // plain write-back: stays in XCD L2
          gdst[0] = d0;
          gdst[1] = d1;
        } else {                         // coherent write-through
          cohstore(gdst, d0);
          cohstore(gdst + 1, d1);
        }
      }
    }

    // ---- round sync: per-block slot store + 32-lane ballot poll
    if (!fast) __builtin_amdgcn_fence(__ATOMIC_RELEASE, "agent");
    __syncthreads();                   // all waves' stores drained (vmcnt 0)
    if (tid == 0) cohstore32(&SLOT[g * 32 + bi], (unsigned)(r + 1));
    if (wave == 0) {
      const unsigned target = (unsigned)(r + 1);
      unsigned spins = 0;
      for (;;) {
        unsigned v = target;
        if (lane < 32) v = cohload32(&SLOT[g * 32 + lane]);
        if (__ballot(v >= target) == ~0ull) break;
        __builtin_amdgcn_s_sleep(2);
        if (++spins > (1u << 20)) break;   // failsafe: wrong-answer beats hang
      }
      if (!fast) __builtin_amdgcn_fence(__ATOMIC_ACQUIRE, "agent");
      asm volatile("" ::: "memory");
    }
    __syncthreads();
  }
}

// ---------------------------------------------------------------------------
extern "C" void kernel_launch(void* const* d_in, const int* in_sizes, int n_in,
                              void* d_out, int out_size, void* d_ws, size_t ws_size,
                              hipStream_t stream) {
  const int*   x        = (const int*)d_in[0];
  const float* Win0     = (const float*)d_in[1];
  const float* Win_rest = (const float*)d_in[2];
  const float* Wc       = (const float*)d_in[3];
  const float* bc       = (const float*)d_in[4];
  const float* Wout     = (const float*)d_in[5];
  const float* bout     = (const float*)d_in[6];
  float* out = (float*)d_out;
  char*  ws  = (char*)d_ws;

  init_kernel<<<512, 256, 0, stream>>>(Wc, Win_rest, ws);
  rnn_persistent<<<NBLK, 512, 0, stream>>>(x, Win0, bc, Wout, bout, ws, out);
}

// Round 12
// 600.318 us; speedup vs baseline: 1.7712x; 1.7712x over previous
//
#include <hip/hip_runtime.h>
#include <cstdint>
#include <cstddef>

// Problem constants
#define B_   1024
#define L_   64
#define H_   512
#define NBLK 256

// Workspace layout (bytes). Total 12,061,696 (~11.5 MiB).
//  WB  : transposed bf16 weights  BT_j[n][k]  (j0: 512x512, j1-3: 512x1024)
//  SB  : state buffers bf16 [layer j][parity], each in A-FRAGMENT TILE ORDER:
//        short index(row,k) = (row>>4)*8192 + (k>>3)*128 + (row&15)*8 + (k&7)
//  BAR : SLOT array: 8 groups x 32 blocks x u32 (128 B per group)
//  XCD : per-block XCC_ID table (256 x u32)
#define WB_OFF   0u
#define SB_OFF   3670016u
#define BAR_OFF  12058624u
#define XCD_OFF  12060672u

typedef __attribute__((ext_vector_type(8))) short short8;
typedef __attribute__((ext_vector_type(4))) float f32x4;
typedef unsigned long long u64;

__device__ __forceinline__ unsigned short f2bf(float f) {
  unsigned u = __float_as_uint(f);
  u += 0x7fffu + ((u >> 16) & 1u);   // RNE
  return (unsigned short)(u >> 16);
}

__device__ __forceinline__ float bf2f(unsigned short s) {
  return __uint_as_float(((unsigned)s) << 16);
}

__device__ __forceinline__ void async16(const void* g, void* l) {
  __builtin_amdgcn_global_load_lds(
      (const __attribute__((address_space(1))) void*)g,
      (__attribute__((address_space(3))) void*)l, 16, 0, 0);
}

// Device-coherent (agent-scope, relaxed) ops: L1-bypass, no fences.
__device__ __forceinline__ u64 cohload(const u64* p) {
  return __hip_atomic_load((u64*)p, __ATOMIC_RELAXED, __HIP_MEMORY_SCOPE_AGENT);
}
__device__ __forceinline__ void cohstore(u64* p, u64 v) {
  __hip_atomic_store(p, v, __ATOMIC_RELAXED, __HIP_MEMORY_SCOPE_AGENT);
}
__device__ __forceinline__ unsigned cohload32(const unsigned* p) {
  return __hip_atomic_load((unsigned*)p, __ATOMIC_RELAXED, __HIP_MEMORY_SCOPE_AGENT);
}
__device__ __forceinline__ void cohstore32(unsigned* p, unsigned v) {
  __hip_atomic_store(p, v, __ATOMIC_RELAXED, __HIP_MEMORY_SCOPE_AGENT);
}

// ---------------------------------------------------------------------------
// Init: transpose+convert weights fp32->bf16 [N][K], zero SB + BAR + XCD.
// ---------------------------------------------------------------------------
__global__ __launch_bounds__(256) void init_kernel(
    const float* __restrict__ Wc, const float* __restrict__ Win_rest,
    char* __restrict__ ws)
{
  const unsigned bb = blockIdx.x;
  const int tid = threadIdx.x;
  if (bb < 448u) {
    __shared__ float tile[64][65];
    int m, tt;
    if (bb < 64u) { m = 0; tt = (int)bb; }
    else { m = 1 + (int)((bb - 64u) >> 7); tt = (int)((bb - 64u) & 127u); }
    const int Km = (m == 0) ? 512 : 1024;
    const int nkt = Km >> 6;
    const int tk = tt % nkt, tn = tt / nkt;
    const int k0 = tk << 6, n0 = tn << 6;
    const int rr = tid >> 4, cc = (tid & 15) << 2;
#pragma unroll
    for (int qq = 0; qq < 4; ++qq) {
      const int row = rr + qq * 16;     // local k
      const int kg = k0 + row;
      const float* src;
      if (m == 0)        src = Wc + (size_t)kg * 512 + n0 + cc;
      else if (kg < 512) src = Wc + ((size_t)m * 512 + kg) * 512 + n0 + cc;
      else               src = Win_rest + ((size_t)(m - 1) * 512 + (kg - 512)) * 512 + n0 + cc;
      const float4 v = *(const float4*)src;
      tile[row][cc + 0] = v.x; tile[row][cc + 1] = v.y;
      tile[row][cc + 2] = v.z; tile[row][cc + 3] = v.w;
    }
    __syncthreads();
    unsigned short* dst = (unsigned short*)(ws + WB_OFF);
    const size_t base = (m == 0) ? 0 : (size_t)262144 + (size_t)(m - 1) * 524288;
#pragma unroll
    for (int qq = 0; qq < 4; ++qq) {
      const int nl = rr + qq * 16;
      const int kl = (tid & 15) << 2;
      ushort4 o;
      o.x = f2bf(tile[kl + 0][nl]); o.y = f2bf(tile[kl + 1][nl]);
      o.z = f2bf(tile[kl + 2][nl]); o.w = f2bf(tile[kl + 3][nl]);
      *(ushort4*)(dst + base + (size_t)(n0 + nl) * Km + k0 + kl) = o;
    }
  } else {
    // zero SB (8,388,608 B) + BAR (1,024 B) + XCD (1,024 B) = 524,416 x 16 B
    f32x4* z = (f32x4*)(ws + SB_OFF);
    const unsigned idx = (bb - 448u) * 256u + (unsigned)tid;
    const f32x4 zero = {0.f, 0.f, 0.f, 0.f};
    for (unsigned u = idx; u < 524480u; u += 16384u) z[u] = zero;
  }
}

// ---------------------------------------------------------------------------
// Persistent kernel. R9 structure (best: 600 us) + two isolated levers:
//  (1) slot-store + ballot-poll barrier (no 32-way atomic RMW chain),
//  (2) 8 independent accumulator chains (accA s=0 / accB s=1, summed in
//      the epilogue) with R9's rolled x4 k-loop and logprob placement.
// 256 blocks x 512 threads = 8 groups x (4 layers x 8 col-slices);
// 8 waves/block (2/SIMD), wave owns 16 batch rows. State in A-fragment
// tile order -> direct global->register A-fragments (1 KB contiguous,
// depth-4 prefetch). k-loop LDS = B-fragment reads only. Cross-block
// exchange: plain L2 write-back stores + L1-bypass loads when the group
// is XCD-uniform (runtime-verified); coherent + fence fallback else.
// ---------------------------------------------------------------------------
__global__ __launch_bounds__(512) void rnn_persistent(
    const int* __restrict__ x, const float* __restrict__ Win0,
    const float* __restrict__ bc, const float* __restrict__ Wout,
    const float* __restrict__ bout, char* __restrict__ ws,
    float* __restrict__ out)
{
  __shared__ short Bperm[16 * 64 * 64];     // 128 KiB persistent weight slice
  __shared__ short Cw[8][16 * 64];          // 16 KiB per-wave epilogue tile

  const int tid = threadIdx.x;
  const int wave = tid >> 6, lane = tid & 63;
  const int blk = (int)blockIdx.x;
  const int g  = blk & 7;            // row-group (XCD-affine under %8 heuristic)
  const int bi = blk >> 3;           // 0..31 within group
  const int j  = bi >> 3;            // layer 0..3
  const int bn = bi & 7;             // col-slice 0..7
  const int bm0 = g * 128;
  const int bn0 = bn * 64;
  const int bnc = bn0 >> 3;                 // first k-chunk our cols map to
  const int rowbase = bm0 + wave * 16;      // this wave's 16 batch rows
  const int rowblk  = rowbase >> 4;         // tile-row index in SB layout

  const unsigned short* WB = (const unsigned short*)(ws + WB_OFF);
  unsigned short* SB = (unsigned short*)(ws + SB_OFF);
  unsigned* SLOT = (unsigned*)(ws + BAR_OFF);
  unsigned* XT = (unsigned*)(ws + XCD_OFF);

  const int Kc = (j == 0) ? 512 : 1024;
  const int nk = Kc >> 6;            // BK = 64: nk = 8 or 16
  const int brow_lp = bm0 + bi * 4 + wave;  // logprob row (waves 0..3 only)

  const int q = lane >> 4, ln = lane & 15;
  const int swz = ln & 7;

  // ---- one-time: pin B slice in LDS (512 threads: one async16 per kk each)
  {
    const unsigned short* Wj = WB + ((j == 0) ? (size_t)0
                                   : ((size_t)262144 + (size_t)(j - 1) * 524288));
    const int nloc = tid >> 3;           // 0..63
    const int lchb = tid & 7;
    const int schunk = lchb ^ (nloc & 7);
    for (int kk = 0; kk < nk; ++kk) {
      async16(Wj + (size_t)(bn0 + nloc) * Kc + (kk << 6) + schunk * 8,
              &Bperm[kk * 4096 + nloc * 64 + lchb * 8]);
    }
  }

  // ---- XCD-affinity check: publish XCC_ID, ballot-poll all 32, verify.
  const unsigned myxcd = __builtin_amdgcn_s_getreg(6164);  // hwreg(20,0,4)
  if (tid == 0) cohstore32(&XT[blk], myxcd + 1u);
  unsigned xv = 1;
  {
    unsigned spins = 0;
    for (;;) {
      xv = 1;
      if (lane < 32) xv = cohload32(&XT[lane * 8 + g]);
      if (__ballot(xv != 0) == ~0ull) break;
      __builtin_amdgcn_s_sleep(2);
      if (++spins > (1u << 20)) break;
    }
  }
  const unsigned xv0 = __shfl(xv, 0);
  const bool fast = (__ballot(lane >= 32 || xv == xv0) == ~0ull);
  __syncthreads();   // also drains this wave's B staging loads

  // ---- hoist per-round-invariant weights into registers
  float wout0[8], wout1[8];
#pragma unroll
  for (int i = 0; i < 8; ++i) {
    const int n = lane * 8 + i;
    wout0[i] = Wout[n * 2 + 0];
    wout1[i] = Wout[n * 2 + 1];
  }
  const float bo0 = bout[0], bo1 = bout[1];
  float bcv[4], w0v[4], w1v[4];
#pragma unroll
  for (int nt = 0; nt < 4; ++nt) {
    const int col = bn0 + ln + nt * 16;
    bcv[nt] = bc[j * H_ + col];
    w0v[nt] = Win0[col];            // xprev == 0 row
    w1v[nt] = Win0[H_ + col];       // xprev == 1 row
  }

  float runLP = 0.f;

#pragma clang loop unroll(disable)
  for (int r = 0; r <= 67; ++r) {
    const int pprev = (r + 1) & 1, pcur = r & 1;
    const int t = r - j;
    const bool active = (t >= 0 && t <= 63);

    const unsigned short* Ssrc = SB + (size_t)(j * 2 + pprev) * (B_ * H_);
    const unsigned short* Psrc = (j > 0)
        ? SB + (size_t)((j - 1) * 2 + pprev) * (B_ * H_) : (const unsigned short*)0;
    unsigned short* Dst = SB + (size_t)(j * 2 + pcur) * (B_ * H_);

    // A-fragment loads straight from global in MFMA layout (SB tile order):
    // for (kk,s) lane(q,ln) reads the 16 B chunk (kc = kbase + s*4 + q,
    // lrow = ln) -> the wave's access is 1 KB fully contiguous.
    // Four static sets -> depth-4 prefetch.
    u64 s0[2][2], s1[2][2], s2[2][2], s3[2][2];
    auto loadTo = [&](int kk, u64 (&st)[2][2]) {
      const int k0 = kk << 6;
      const unsigned short* Asrc; int ak0;
      if (k0 < 512) { Asrc = Ssrc; ak0 = k0; } else { Asrc = Psrc; ak0 = k0 - 512; }
      const int kc0 = ak0 >> 3;
#pragma unroll
      for (int s = 0; s < 2; ++s) {
        const u64* gp = (const u64*)(Asrc + (size_t)rowblk * 8192
                                     + (size_t)(kc0 + s * 4 + q) * 128 + ln * 8);
        st[s][0] = cohload(gp);
        st[s][1] = cohload(gp + 1);
      }
    };
    // 8 independent accumulator chains: accA for s=0, accB for s=1.
    f32x4 accA[4] = {};
    f32x4 accB[4] = {};
    auto kstep = [&](int kk, u64 (&st)[2][2]) {
      short8 af0, af1;
      __builtin_memcpy(&af0, &st[0][0], 16);
      __builtin_memcpy(&af1, &st[1][0], 16);
      if (kk + 4 < nk) loadTo(kk + 4, st);    // refill same set, 4 ahead
      const short* Bb = &Bperm[kk * 4096];
#pragma unroll
      for (int nt = 0; nt < 4; ++nt) {
        const short8 b0 = *(const short8*)(Bb + (nt * 16 + ln) * 64
                                           + (q ^ swz) * 8);
        accA[nt] = __builtin_amdgcn_mfma_f32_16x16x32_bf16(af0, b0, accA[nt], 0, 0, 0);
      }
#pragma unroll
      for (int nt = 0; nt < 4; ++nt) {
        const short8 b1 = *(const short8*)(Bb + (nt * 16 + ln) * 64
                                           + ((4 | q) ^ swz) * 8);
        accB[nt] = __builtin_amdgcn_mfma_f32_16x16x32_bf16(af1, b1, accB[nt], 0, 0, 0);
      }
    };

    if (active) { loadTo(0, s0); loadTo(1, s1); loadTo(2, s2); loadTo(3, s3); }

    // ---- logprob for t' = r-4 (waves 0..3): lane reads chunk kc=lane of
    // row brow_lp in tile order (n = lane*8 + i, matching wout regs).
    if (r >= 4 && wave < 4) {
      const int tl = r - 4;
      const unsigned short* h3 = SB + (size_t)(3 * 2 + pprev) * (B_ * H_)
                                    + (size_t)(brow_lp >> 4) * 8192
                                    + (size_t)(brow_lp & 15) * 8;
      const u64* hp = (const u64*)(h3 + (size_t)lane * 128);
      const u64 hw0 = cohload(hp);
      const u64 hw1 = cohload(hp + 1);
      float z0 = 0.f, z1 = 0.f;
#pragma unroll
      for (int i = 0; i < 8; ++i) {
        const u64 hw = (i < 4) ? hw0 : hw1;
        const float h = bf2f((unsigned short)((hw >> (16 * (i & 3))) & 0xffffu));
        z0 = fmaf(h, wout0[i], z0);
        z1 = fmaf(h, wout1[i], z1);
      }
#pragma unroll
      for (int off = 32; off > 0; off >>= 1) {
        z0 += __shfl_down(z0, off);
        z1 += __shfl_down(z1, off);
      }
      if (lane == 0) {
        z0 += bo0; z1 += bo1;
        const float mx = fmaxf(z0, z1), mn = fminf(z0, z1);
        const float lse = mx + log1pf(__expf(mn - mx));
        const int xt = x[brow_lp * L_ + tl];
        float lp = ((xt == 0) ? z0 : z1) - lse;
        if (!(lp == lp)) lp = -35.0f;   // nan_to_num
        runLP += lp;
        if (tl == 63) out[brow_lp] = 0.5f * runLP;   // LOG_PROB_FACTOR
      }
    }

    // ---- GEMM cell (t, j): wave-local, sync-free, rolled x4 k-loop
    if (active) {
      for (int kk = 0; kk < nk; kk += 4) {
        kstep(kk + 0, s0);
        kstep(kk + 1, s1);
        kstep(kk + 2, s2);
        kstep(kk + 3, s3);
      }

      // per-wave epilogue: bias (+Win0) + elu -> swizzled Ctile -> stores
      short* Ctile = &Cw[wave][0];
#pragma unroll
      for (int i = 0; i < 4; ++i) {
        const int lr = q * 4 + i;        // local row 0..15
        const int brow = rowbase + lr;
        int xprev = 0;
        if (j == 0 && t > 0) xprev = x[brow * L_ + (t - 1)];
#pragma unroll
        for (int nt = 0; nt < 4; ++nt) {
          float pre = accA[nt][i] + accB[nt][i] + bcv[nt];
          if (j == 0 && t > 0) pre += (xprev ? w1v[nt] : w0v[nt]);
          const float h = (pre > 0.f) ? pre : (__expf(pre) - 1.0f);
          const int chunkcol = nt * 2 + (ln >> 3);
          Ctile[lr * 64 + (chunkcol ^ (lr & 7)) * 8 + (ln & 7)] = (short)f2bf(h);
        }
      }
      // write out in SB tile order, fully coalesced (1 KB per instruction).
      // same-wave DS in-order: Ctile readback needs no barrier.
      const int lrs = ln;                 // row 0..15
#pragma unroll
      for (int it = 0; it < 2; ++it) {
        const int ch = q + it * 4;        // our k-chunk 0..7 (cols bn0+ch*8)
        const u64* p = (const u64*)(Ctile + lrs * 64 + (ch ^ (lrs & 7)) * 8);
        const u64 d0 = p[0], d1 = p[1];
        u64* gdst = (u64*)(Dst + (size_t)rowblk * 8192
                           + (size_t)(bnc + ch) * 128 + lrs * 8);
        if (fast) {                      // plain write-back: stays in XCD L2
          gdst[0] = d0;
          gdst[1] = d1;
        } else {                         // coherent write-through
          cohstore(gdst, d0);
          cohstore(gdst + 1, d1);
        }
      }
    }

    // ---- round sync: per-block slot store + 32-lane ballot poll
    if (!fast) __builtin_amdgcn_fence(__ATOMIC_RELEASE, "agent");
    __syncthreads();                   // all waves' stores drained (vmcnt 0)
    if (tid == 0) cohstore32(&SLOT[g * 32 + bi], (unsigned)(r + 1));
    if (wave == 0) {
      const unsigned target = (unsigned)(r + 1);
      unsigned spins = 0;
      for (;;) {
        unsigned v = target;
        if (lane < 32) v = cohload32(&SLOT[g * 32 + lane]);
        if (__ballot(v >= target) == ~0ull) break;
        __builtin_amdgcn_s_sleep(2);
        if (++spins > (1u << 20)) break;   // failsafe: wrong-answer beats hang
      }
      if (!fast) __builtin_amdgcn_fence(__ATOMIC_ACQUIRE, "agent");
      asm volatile("" ::: "memory");
    }
    __syncthreads();
  }
}

// ---------------------------------------------------------------------------
extern "C" void kernel_launch(void* const* d_in, const int* in_sizes, int n_in,
                              void* d_out, int out_size, void* d_ws, size_t ws_size,
                              hipStream_t stream) {
  const int*   x        = (const int*)d_in[0];
  const float* Win0     = (const float*)d_in[1];
  const float* Win_rest = (const float*)d_in[2];
  const float* Wc       = (const float*)d_in[3];
  const float* bc       = (const float*)d_in[4];
  const float* Wout     = (const float*)d_in[5];
  const float* bout     = (const float*)d_in[6];
  float* out = (float*)d_out;
  char*  ws  = (char*)d_ws;

  init_kernel<<<512, 256, 0, stream>>>(Wc, Win_rest, ws);
  rnn_persistent<<<NBLK, 512, 0, stream>>>(x, Win0, bc, Wout, bout, ws, out);
}